// Round 1
// baseline (182.894 us; speedup 1.0000x reference)
//
#include <hip/hip_runtime.h>
#include <stdint.h>

#define INS 768
#define OUTS 64
#define BB 8
#define SS 2048

typedef __attribute__((ext_vector_type(8))) short short8;
typedef __attribute__((ext_vector_type(4))) float f32x4;

__device__ inline unsigned short f2bf(float f) {
  union { float f; uint32_t u; } v; v.f = f;
  uint32_t r = v.u + 0x7FFFu + ((v.u >> 16) & 1u);  // RNE
  return (unsigned short)(r >> 16);
}

// ---------------- kernel 1: cast + transpose weights, fold 1/8 into Wq/bq ----
__global__ void cast_weights(const float* __restrict__ Wq, const float* __restrict__ bq,
                             const float* __restrict__ Wk, const float* __restrict__ bk,
                             const float* __restrict__ Wv, const float* __restrict__ bv,
                             unsigned short* __restrict__ Wt, float* __restrict__ bc) {
  int n = blockIdx.x;                 // 0..191 output channel (q|k|v)
  const float* W; const float* bs; float scale; int nl;
  if (n < 64)       { W = Wq; bs = bq; scale = 0.125f; nl = n; }
  else if (n < 128) { W = Wk; bs = bk; scale = 1.0f;   nl = n - 64; }
  else              { W = Wv; bs = bv; scale = 1.0f;   nl = n - 128; }
  for (int k = threadIdx.x; k < INS; k += blockDim.x)
    Wt[(size_t)n*INS + k] = f2bf(W[(size_t)k*OUTS + nl] * scale);
  if (threadIdx.x == 0) bc[n] = bs[nl] * scale;
}

// ---------------- kernel 2: fused QKV projection GEMM (M=16384,N=192,K=768) --
#define BK1 32
#define LDX 40   // padded LDS row stride (bf16 elems) -> 2-way-max bank aliasing
#define LDW 40

__global__ __launch_bounds__(256) void qkv_gemm(
    const float* __restrict__ X, const unsigned short* __restrict__ Wt,
    const float* __restrict__ bc,
    unsigned short* __restrict__ Qg, unsigned short* __restrict__ Kg,
    unsigned short* __restrict__ Vtg) {
  __shared__ __align__(16) unsigned short Xs[64 * LDX];
  __shared__ __align__(16) unsigned short Ws[192 * LDW];
  const int tid  = threadIdx.x;
  const int wave = tid >> 6, lane = tid & 63;
  const int quad = lane >> 4, l16 = lane & 15;
  const int row0 = blockIdx.x * 64;

  f32x4 acc[12];
#pragma unroll
  for (int i = 0; i < 12; ++i) acc[i] = (f32x4){0.f, 0.f, 0.f, 0.f};

  for (int kt = 0; kt < INS; kt += BK1) {
    // stage X tile (64 rows x 32 floats), convert fp32->bf16 inline
#pragma unroll
    for (int rep = 0; rep < 2; ++rep) {
      int f = tid + rep * 256;
      int r = f >> 3, c4 = f & 7;
      float4 v = *reinterpret_cast<const float4*>(X + (size_t)(row0 + r) * INS + kt + c4 * 4);
      unsigned short* dst = &Xs[r * LDX + c4 * 4];
      dst[0] = f2bf(v.x); dst[1] = f2bf(v.y); dst[2] = f2bf(v.z); dst[3] = f2bf(v.w);
    }
    // stage W tile (192 rows x 32 bf16), n-major so B-frags are contiguous
#pragma unroll
    for (int rep = 0; rep < 3; ++rep) {
      int c = tid + rep * 256;
      int n = c >> 2, c16 = c & 3;
      *reinterpret_cast<int4*>(&Ws[n * LDW + c16 * 8]) =
          *reinterpret_cast<const int4*>(Wt + (size_t)n * INS + kt + c16 * 8);
    }
    __syncthreads();
    short8 a = *reinterpret_cast<const short8*>(&Xs[(wave * 16 + l16) * LDX + quad * 8]);
#pragma unroll
    for (int nt = 0; nt < 12; ++nt) {
      short8 b = *reinterpret_cast<const short8*>(&Ws[(nt * 16 + l16) * LDW + quad * 8]);
      acc[nt] = __builtin_amdgcn_mfma_f32_16x16x32_bf16(a, b, acc[nt], 0, 0, 0);
    }
    __syncthreads();
  }
  // epilogue: Q,K row-major bf16; V transposed (Vt[batch][d][s])
  const int gm0 = row0 + wave * 16 + quad * 4;
#pragma unroll
  for (int nt = 0; nt < 12; ++nt) {
    const int n = nt * 16 + l16;
    const float bias = bc[n];
    if (nt < 8) {
      unsigned short* dstbase = (nt < 4) ? Qg : Kg;
      const int nn = (nt < 4) ? n : (n - 64);
#pragma unroll
      for (int r = 0; r < 4; ++r)
        dstbase[(size_t)(gm0 + r) * OUTS + nn] = f2bf(acc[nt][r] + bias);
    } else {
      const int d = n - 128;
      const int batch = gm0 >> 11, s0 = gm0 & 2047;
      ushort4 pk;
      pk.x = f2bf(acc[nt][0] + bias);
      pk.y = f2bf(acc[nt][1] + bias);
      pk.z = f2bf(acc[nt][2] + bias);
      pk.w = f2bf(acc[nt][3] + bias);
      *reinterpret_cast<ushort4*>(&Vtg[((size_t)batch * OUTS + d) * SS + s0]) = pk;
    }
  }
}

// ---------------- kernel 3: attention (no max-subtraction; scores are small) -
#define LDK 72
#define LDV 136
#define LDP 136

__global__ __launch_bounds__(256) void attn(
    const unsigned short* __restrict__ Qg, const unsigned short* __restrict__ Kg,
    const unsigned short* __restrict__ Vtg, float* __restrict__ out) {
  __shared__ __align__(16) unsigned short Ks[128 * LDK];
  __shared__ __align__(16) unsigned short Vts[64 * LDV];
  __shared__ __align__(16) unsigned short Ps[4][16 * LDP];
  const int tid  = threadIdx.x;
  const int wave = tid >> 6, lane = tid & 63;
  const int quad = lane >> 4, l16 = lane & 15;
  const int bt = blockIdx.x >> 5, qt = blockIdx.x & 31;
  const int q0 = qt * 64;
  const unsigned short* Qb = Qg + (size_t)bt * SS * OUTS;
  const unsigned short* Kb = Kg + (size_t)bt * SS * OUTS;
  const unsigned short* Vb = Vtg + (size_t)bt * OUTS * SS;

  // Q A-fragments (16 q-rows per wave), loaded once. Q already scaled by 1/8.
  short8 aq[2];
#pragma unroll
  for (int ks = 0; ks < 2; ++ks)
    aq[ks] = *reinterpret_cast<const short8*>(
        Qb + (size_t)(q0 + wave * 16 + l16) * OUTS + ks * 32 + quad * 8);

  f32x4 oacc[4];
#pragma unroll
  for (int i = 0; i < 4; ++i) oacc[i] = (f32x4){0.f, 0.f, 0.f, 0.f};
  float lsum[4] = {0.f, 0.f, 0.f, 0.f};

  for (int j0 = 0; j0 < SS; j0 += 128) {
    // stage K tile: 128 keys x 64 d
#pragma unroll
    for (int rep = 0; rep < 4; ++rep) {
      int c = tid + rep * 256;
      int r = c >> 3, ch = c & 7;
      *reinterpret_cast<int4*>(&Ks[r * LDK + ch * 8]) =
          *reinterpret_cast<const int4*>(Kb + (size_t)(j0 + r) * OUTS + ch * 8);
    }
    // stage Vt tile: 64 d x 128 keys
#pragma unroll
    for (int rep = 0; rep < 4; ++rep) {
      int c = tid + rep * 256;
      int d = c >> 4, ch = c & 15;
      *reinterpret_cast<int4*>(&Vts[d * LDV + ch * 8]) =
          *reinterpret_cast<const int4*>(Vb + (size_t)d * SS + j0 + ch * 8);
    }
    __syncthreads();

    // S = Q K^T (pre-scaled)
    f32x4 sc[8];
#pragma unroll
    for (int nt = 0; nt < 8; ++nt) sc[nt] = (f32x4){0.f, 0.f, 0.f, 0.f};
#pragma unroll
    for (int ks = 0; ks < 2; ++ks) {
#pragma unroll
      for (int nt = 0; nt < 8; ++nt) {
        short8 b = *reinterpret_cast<const short8*>(&Ks[(nt * 16 + l16) * LDK + ks * 32 + quad * 8]);
        sc[nt] = __builtin_amdgcn_mfma_f32_16x16x32_bf16(aq[ks], b, sc[nt], 0, 0, 0);
      }
    }

    // P = exp(S); running row sums
    float p[8][4];
    float rs[4] = {0.f, 0.f, 0.f, 0.f};
#pragma unroll
    for (int nt = 0; nt < 8; ++nt)
#pragma unroll
      for (int r = 0; r < 4; ++r) { p[nt][r] = __expf(sc[nt][r]); rs[r] += p[nt][r]; }
#pragma unroll
    for (int st = 1; st < 16; st <<= 1)
#pragma unroll
      for (int r = 0; r < 4; ++r) rs[r] += __shfl_xor(rs[r], st, 64);
#pragma unroll
    for (int r = 0; r < 4; ++r) lsum[r] += rs[r];

    // C-layout -> A-layout via wave-private LDS round trip
    unsigned short* Pw = Ps[wave];
#pragma unroll
    for (int nt = 0; nt < 8; ++nt)
#pragma unroll
      for (int r = 0; r < 4; ++r)
        Pw[(quad * 4 + r) * LDP + nt * 16 + l16] = f2bf(p[nt][r]);

    // O += P V
#pragma unroll
    for (int ks = 0; ks < 4; ++ks) {
      short8 a = *reinterpret_cast<const short8*>(&Pw[l16 * LDP + ks * 32 + quad * 8]);
#pragma unroll
      for (int nt = 0; nt < 4; ++nt) {
        short8 b = *reinterpret_cast<const short8*>(&Vts[(nt * 16 + l16) * LDV + ks * 32 + quad * 8]);
        oacc[nt] = __builtin_amdgcn_mfma_f32_16x16x32_bf16(a, b, oacc[nt], 0, 0, 0);
      }
    }
    __syncthreads();
  }

#pragma unroll
  for (int nt = 0; nt < 4; ++nt)
#pragma unroll
    for (int r = 0; r < 4; ++r) {
      int q = q0 + wave * 16 + quad * 4 + r;
      out[((size_t)bt * SS + q) * OUTS + nt * 16 + l16] = oacc[nt][r] / lsum[r];
    }
}

extern "C" void kernel_launch(void* const* d_in, const int* in_sizes, int n_in,
                              void* d_out, int out_size, void* d_ws, size_t ws_size,
                              hipStream_t stream) {
  const float* X  = (const float*)d_in[0];
  const float* Wq = (const float*)d_in[1];
  const float* bq = (const float*)d_in[2];
  const float* Wk = (const float*)d_in[3];
  const float* bk = (const float*)d_in[4];
  const float* Wv = (const float*)d_in[5];
  const float* bv = (const float*)d_in[6];
  float* out = (float*)d_out;

  char* ws = (char*)d_ws;
  unsigned short* Qg  = (unsigned short*)(ws);                              // 2 MB
  unsigned short* Kg  = (unsigned short*)(ws + (size_t)2 * 1024 * 1024);    // 2 MB
  unsigned short* Vtg = (unsigned short*)(ws + (size_t)4 * 1024 * 1024);    // 2 MB
  unsigned short* Wt  = (unsigned short*)(ws + (size_t)6 * 1024 * 1024);    // 288 KB
  float*          bc  = (float*)(ws + (size_t)6 * 1024 * 1024 + 294912);    // 768 B

  cast_weights<<<192, 256, 0, stream>>>(Wq, bq, Wk, bk, Wv, bv, Wt, bc);
  qkv_gemm<<<256, 256, 0, stream>>>(X, Wt, bc, Qg, Kg, Vtg);
  attn<<<256, 256, 0, stream>>>(Qg, Kg, Vtg, out);
}

// Round 2
// 180.789 us; speedup vs baseline: 1.0116x; 1.0116x over previous
//
#include <hip/hip_runtime.h>
#include <stdint.h>

#define INS 768
#define OUTS 64
#define BB 8
#define SS 2048

typedef __attribute__((ext_vector_type(8))) short short8;
typedef __attribute__((ext_vector_type(4))) float f32x4;

__device__ inline unsigned short f2bf(float f) {
  union { float f; uint32_t u; } v; v.f = f;
  uint32_t r = v.u + 0x7FFFu + ((v.u >> 16) & 1u);  // RNE
  return (unsigned short)(r >> 16);
}

// ---------------- kernel 1: cast + transpose weights, fold 1/8 into Wq/bq ----
__global__ void cast_weights(const float* __restrict__ Wq, const float* __restrict__ bq,
                             const float* __restrict__ Wk, const float* __restrict__ bk,
                             const float* __restrict__ Wv, const float* __restrict__ bv,
                             unsigned short* __restrict__ Wt, float* __restrict__ bc) {
  int n = blockIdx.x;                 // 0..191 output channel (q|k|v)
  const float* W; const float* bs; float scale; int nl;
  if (n < 64)       { W = Wq; bs = bq; scale = 0.125f; nl = n; }
  else if (n < 128) { W = Wk; bs = bk; scale = 1.0f;   nl = n - 64; }
  else              { W = Wv; bs = bv; scale = 1.0f;   nl = n - 128; }
  for (int k = threadIdx.x; k < INS; k += blockDim.x)
    Wt[(size_t)n*INS + k] = f2bf(W[(size_t)k*OUTS + nl] * scale);
  if (threadIdx.x == 0) bc[n] = bs[nl] * scale;
}

// ---------------- kernel 2: fused QKV projection GEMM (M=16384,N=192,K=768) --
// M-tile 32, BK=64, grid 512 (2 blocks/CU), register-prefetch double buffer.
#define LD2 72   // padded LDS row stride (bf16): 36 dwords -> max 2-way aliasing (free)

__global__ __launch_bounds__(256) void qkv_gemm(
    const float* __restrict__ X, const unsigned short* __restrict__ Wt,
    const float* __restrict__ bc,
    unsigned short* __restrict__ Qg, unsigned short* __restrict__ Kg,
    unsigned short* __restrict__ Vtg) {
  __shared__ __align__(16) unsigned short Xs[32 * LD2];
  __shared__ __align__(16) unsigned short Ws[192 * LD2];
  const int tid  = threadIdx.x;
  const int wave = tid >> 6, lane = tid & 63;
  const int quad = lane >> 4, l16 = lane & 15;
  const int wr = wave & 1, wn = wave >> 1;   // row-half / N-half per wave
  const int row0 = blockIdx.x * 32;

  f32x4 acc[6];
#pragma unroll
  for (int i = 0; i < 6; ++i) acc[i] = (f32x4){0.f, 0.f, 0.f, 0.f};

  float4 xr[2];
  int4   wv[6];
  // prefetch tile 0
#pragma unroll
  for (int rep = 0; rep < 2; ++rep) {
    int f = tid + rep * 256, r = f >> 4, c4 = f & 15;
    xr[rep] = *reinterpret_cast<const float4*>(X + (size_t)(row0 + r) * INS + c4 * 4);
  }
#pragma unroll
  for (int rep = 0; rep < 6; ++rep) {
    int c = tid + rep * 256, n = c >> 3, ch = c & 7;
    wv[rep] = *reinterpret_cast<const int4*>(Wt + (size_t)n * INS + ch * 8);
  }

  for (int it = 0; it < 12; ++it) {
    if (it) __syncthreads();
    // store prefetched tile to LDS (fp32->bf16 for X)
#pragma unroll
    for (int rep = 0; rep < 2; ++rep) {
      int f = tid + rep * 256, r = f >> 4, c4 = f & 15;
      unsigned short* dst = &Xs[r * LD2 + c4 * 4];
      dst[0] = f2bf(xr[rep].x); dst[1] = f2bf(xr[rep].y);
      dst[2] = f2bf(xr[rep].z); dst[3] = f2bf(xr[rep].w);
    }
#pragma unroll
    for (int rep = 0; rep < 6; ++rep) {
      int c = tid + rep * 256, n = c >> 3, ch = c & 7;
      *reinterpret_cast<int4*>(&Ws[n * LD2 + ch * 8]) = wv[rep];
    }
    __syncthreads();
    // issue next tile's global loads (overlap with MFMA below)
    if (it + 1 < 12) {
      const int kt = (it + 1) * 64;
#pragma unroll
      for (int rep = 0; rep < 2; ++rep) {
        int f = tid + rep * 256, r = f >> 4, c4 = f & 15;
        xr[rep] = *reinterpret_cast<const float4*>(X + (size_t)(row0 + r) * INS + kt + c4 * 4);
      }
#pragma unroll
      for (int rep = 0; rep < 6; ++rep) {
        int c = tid + rep * 256, n = c >> 3, ch = c & 7;
        wv[rep] = *reinterpret_cast<const int4*>(Wt + (size_t)n * INS + kt + ch * 8);
      }
    }
#pragma unroll
    for (int ks = 0; ks < 2; ++ks) {
      short8 a = *reinterpret_cast<const short8*>(&Xs[(wr * 16 + l16) * LD2 + ks * 32 + quad * 8]);
#pragma unroll
      for (int nt = 0; nt < 6; ++nt) {
        short8 b = *reinterpret_cast<const short8*>(&Ws[(wn * 96 + nt * 16 + l16) * LD2 + ks * 32 + quad * 8]);
        acc[nt] = __builtin_amdgcn_mfma_f32_16x16x32_bf16(a, b, acc[nt], 0, 0, 0);
      }
    }
  }
  // epilogue: Q,K row-major bf16; V transposed (Vt[batch][d][s])
  const int gm0 = row0 + wr * 16 + quad * 4;
#pragma unroll
  for (int nt = 0; nt < 6; ++nt) {
    const int n = wn * 96 + nt * 16 + l16;
    const float bias = bc[n];
    if (n < 128) {
      unsigned short* dstbase = (n < 64) ? Qg : Kg;
      const int nn = n & 63;
#pragma unroll
      for (int r = 0; r < 4; ++r)
        dstbase[(size_t)(gm0 + r) * OUTS + nn] = f2bf(acc[nt][r] + bias);
    } else {
      const int d = n - 128;
      const int batch = gm0 >> 11, s0 = gm0 & 2047;
      ushort4 pk;
      pk.x = f2bf(acc[nt][0] + bias);
      pk.y = f2bf(acc[nt][1] + bias);
      pk.z = f2bf(acc[nt][2] + bias);
      pk.w = f2bf(acc[nt][3] + bias);
      *reinterpret_cast<ushort4*>(&Vtg[((size_t)batch * OUTS + d) * SS + s0]) = pk;
    }
  }
}

// ---------------- kernel 3: attention, key-split x4 ---------------------------
// grid = 8 batches x 32 q-tiles x 4 key-splits = 1024 blocks; 27.6KB LDS -> 5 blocks/CU
#define LDA 72

__global__ __launch_bounds__(256) void attn(
    const unsigned short* __restrict__ Qg, const unsigned short* __restrict__ Kg,
    const unsigned short* __restrict__ Vtg,
    float* __restrict__ OP, float* __restrict__ LS) {
  __shared__ __align__(16) unsigned short Ks[64 * LDA];
  __shared__ __align__(16) unsigned short Vts[64 * LDA];
  __shared__ __align__(16) unsigned short Ps[4][16 * LDA];
  const int tid  = threadIdx.x;
  const int wave = tid >> 6, lane = tid & 63;
  const int quad = lane >> 4, l16 = lane & 15;
  const int ksl = blockIdx.x & 3;
  const int qt  = (blockIdx.x >> 2) & 31;
  const int bt  = blockIdx.x >> 7;
  const int q0 = qt * 64;
  const unsigned short* Qb = Qg + (size_t)bt * SS * OUTS;
  const unsigned short* Kb = Kg + (size_t)bt * SS * OUTS;
  const unsigned short* Vb = Vtg + (size_t)bt * OUTS * SS;

  // Q A-fragments (16 q-rows per wave), loaded once. Q pre-scaled by 1/8.
  short8 aq[2];
#pragma unroll
  for (int ks = 0; ks < 2; ++ks)
    aq[ks] = *reinterpret_cast<const short8*>(
        Qb + (size_t)(q0 + wave * 16 + l16) * OUTS + ks * 32 + quad * 8);

  f32x4 oacc[4];
#pragma unroll
  for (int i = 0; i < 4; ++i) oacc[i] = (f32x4){0.f, 0.f, 0.f, 0.f};
  float lsum[4] = {0.f, 0.f, 0.f, 0.f};

  const int jbeg = ksl * 512;
  for (int j0 = jbeg; j0 < jbeg + 512; j0 += 64) {
    // stage K tile: 64 keys x 64 d
#pragma unroll
    for (int rep = 0; rep < 2; ++rep) {
      int c = tid + rep * 256, r = c >> 3, ch = c & 7;
      *reinterpret_cast<int4*>(&Ks[r * LDA + ch * 8]) =
          *reinterpret_cast<const int4*>(Kb + (size_t)(j0 + r) * OUTS + ch * 8);
    }
    // stage Vt tile: 64 d x 64 keys
#pragma unroll
    for (int rep = 0; rep < 2; ++rep) {
      int c = tid + rep * 256, d = c >> 3, ch = c & 7;
      *reinterpret_cast<int4*>(&Vts[d * LDA + ch * 8]) =
          *reinterpret_cast<const int4*>(Vb + (size_t)d * SS + j0 + ch * 8);
    }
    __syncthreads();

    // S = Q K^T (pre-scaled)
    f32x4 sc[4];
#pragma unroll
    for (int nt = 0; nt < 4; ++nt) sc[nt] = (f32x4){0.f, 0.f, 0.f, 0.f};
#pragma unroll
    for (int ks = 0; ks < 2; ++ks)
#pragma unroll
      for (int nt = 0; nt < 4; ++nt) {
        short8 b = *reinterpret_cast<const short8*>(&Ks[(nt * 16 + l16) * LDA + ks * 32 + quad * 8]);
        sc[nt] = __builtin_amdgcn_mfma_f32_16x16x32_bf16(aq[ks], b, sc[nt], 0, 0, 0);
      }

    // P = exp(S); running row sums (scores small: no max-subtraction needed)
    float p[4][4];
    float rs[4] = {0.f, 0.f, 0.f, 0.f};
#pragma unroll
    for (int nt = 0; nt < 4; ++nt)
#pragma unroll
      for (int r = 0; r < 4; ++r) { p[nt][r] = __expf(sc[nt][r]); rs[r] += p[nt][r]; }
#pragma unroll
    for (int st = 1; st < 16; st <<= 1)
#pragma unroll
      for (int r = 0; r < 4; ++r) rs[r] += __shfl_xor(rs[r], st, 64);
#pragma unroll
    for (int r = 0; r < 4; ++r) lsum[r] += rs[r];

    // C-layout -> A-layout via wave-private LDS round trip
    unsigned short* Pw = Ps[wave];
#pragma unroll
    for (int nt = 0; nt < 4; ++nt)
#pragma unroll
      for (int r = 0; r < 4; ++r)
        Pw[(quad * 4 + r) * LDA + nt * 16 + l16] = f2bf(p[nt][r]);

    // O += P V
#pragma unroll
    for (int ks = 0; ks < 2; ++ks) {
      short8 a = *reinterpret_cast<const short8*>(&Pw[l16 * LDA + ks * 32 + quad * 8]);
#pragma unroll
      for (int nt = 0; nt < 4; ++nt) {
        short8 b = *reinterpret_cast<const short8*>(&Vts[(nt * 16 + l16) * LDA + ks * 32 + quad * 8]);
        oacc[nt] = __builtin_amdgcn_mfma_f32_16x16x32_bf16(a, b, oacc[nt], 0, 0, 0);
      }
    }
    __syncthreads();
  }

  // write partials: OP[ksl][bt][q][d], LS[ksl][bt*S+q]
  float* OPb = OP + ((size_t)ksl * BB + bt) * SS * OUTS;
#pragma unroll
  for (int nt = 0; nt < 4; ++nt)
#pragma unroll
    for (int r = 0; r < 4; ++r) {
      int q = q0 + wave * 16 + quad * 4 + r;
      OPb[(size_t)q * OUTS + nt * 16 + l16] = oacc[nt][r];
    }
  if (l16 == 0) {
#pragma unroll
    for (int r = 0; r < 4; ++r)
      LS[(size_t)ksl * BB * SS + bt * SS + q0 + wave * 16 + quad * 4 + r] = lsum[r];
  }
}

// ---------------- kernel 4: combine key-split partials -----------------------
__global__ __launch_bounds__(256) void combine(
    const float* __restrict__ OP, const float* __restrict__ LS,
    float* __restrict__ out) {
  const size_t i4 = (size_t)blockIdx.x * 256 + threadIdx.x;  // float4 index
  const size_t row = (i4 * 4) >> 6;                          // bt*S + q
  float4 o = make_float4(0.f, 0.f, 0.f, 0.f);
  float l = 0.f;
#pragma unroll
  for (int ks = 0; ks < 4; ++ks) {
    float4 t = reinterpret_cast<const float4*>(OP + (size_t)ks * BB * SS * OUTS)[i4];
    o.x += t.x; o.y += t.y; o.z += t.z; o.w += t.w;
    l += LS[(size_t)ks * BB * SS + row];
  }
  const float inv = 1.0f / l;
  float4 res = make_float4(o.x * inv, o.y * inv, o.z * inv, o.w * inv);
  reinterpret_cast<float4*>(out)[i4] = res;
}

extern "C" void kernel_launch(void* const* d_in, const int* in_sizes, int n_in,
                              void* d_out, int out_size, void* d_ws, size_t ws_size,
                              hipStream_t stream) {
  const float* X  = (const float*)d_in[0];
  const float* Wq = (const float*)d_in[1];
  const float* bq = (const float*)d_in[2];
  const float* Wk = (const float*)d_in[3];
  const float* bk = (const float*)d_in[4];
  const float* Wv = (const float*)d_in[5];
  const float* bv = (const float*)d_in[6];
  float* out = (float*)d_out;

  char* ws = (char*)d_ws;
  unsigned short* Qg  = (unsigned short*)(ws);                              // 2 MB
  unsigned short* Kg  = (unsigned short*)(ws + (size_t)2 * 1024 * 1024);    // 2 MB
  unsigned short* Vtg = (unsigned short*)(ws + (size_t)4 * 1024 * 1024);    // 2 MB
  unsigned short* Wt  = (unsigned short*)(ws + (size_t)6 * 1024 * 1024);    // 288 KB
  float*          bc  = (float*)(ws + (size_t)6 * 1024 * 1024 + 294912);    // 768 B
  float*          OP  = (float*)(ws + (size_t)7 * 1024 * 1024);             // 16 MB
  float*          LS  = (float*)(ws + (size_t)23 * 1024 * 1024);            // 256 KB

  cast_weights<<<192, 256, 0, stream>>>(Wq, bq, Wk, bk, Wv, bv, Wt, bc);
  qkv_gemm<<<512, 256, 0, stream>>>(X, Wt, bc, Qg, Kg, Vtg);
  attn<<<1024, 256, 0, stream>>>(Qg, Kg, Vtg, OP, LS);
  combine<<<1024, 256, 0, stream>>>(OP, LS, out);
}

// Round 3
// 174.488 us; speedup vs baseline: 1.0482x; 1.0361x over previous
//
#include <hip/hip_runtime.h>
#include <stdint.h>

#define INS 768
#define OUTS 64
#define BB 8
#define SS 2048

typedef __attribute__((ext_vector_type(8))) short short8;
typedef __attribute__((ext_vector_type(4))) float f32x4;

__device__ inline unsigned short f2bf(float f) {
  union { float f; uint32_t u; } v; v.f = f;
  uint32_t r = v.u + 0x7FFFu + ((v.u >> 16) & 1u);  // RNE
  return (unsigned short)(r >> 16);
}

__device__ inline short8 cvt8(float4 a, float4 b) {
  short8 r;
  r[0] = (short)f2bf(a.x); r[1] = (short)f2bf(a.y);
  r[2] = (short)f2bf(a.z); r[3] = (short)f2bf(a.w);
  r[4] = (short)f2bf(b.x); r[5] = (short)f2bf(b.y);
  r[6] = (short)f2bf(b.z); r[7] = (short)f2bf(b.w);
  return r;
}

// ---------------- kernel 1: tiled transpose-cast of weights ------------------
// grid 36 = 3 mats x 12 k-tiles. Coalesced fp32 reads, LDS transpose, coalesced
// bf16 writes. Folds 1/8 into Wq/bq.
__global__ __launch_bounds__(256) void cast_weights(
    const float* __restrict__ Wq, const float* __restrict__ bq,
    const float* __restrict__ Wk, const float* __restrict__ bk,
    const float* __restrict__ Wv, const float* __restrict__ bv,
    unsigned short* __restrict__ Wt, float* __restrict__ bc) {
  __shared__ float Ls[64][65];
  const int mat = blockIdx.x / 12, kt = blockIdx.x % 12;
  const float* W; const float* bs; float scale;
  if (mat == 0)      { W = Wq; bs = bq; scale = 0.125f; }
  else if (mat == 1) { W = Wk; bs = bk; scale = 1.0f; }
  else               { W = Wv; bs = bv; scale = 1.0f; }
  const int tid = threadIdx.x;
#pragma unroll
  for (int rep = 0; rep < 4; ++rep) {
    int idx = tid + rep * 256, r = idx >> 4, c4 = idx & 15;
    float4 v = *reinterpret_cast<const float4*>(W + (size_t)(kt * 64 + r) * 64 + c4 * 4);
    Ls[r][c4 * 4 + 0] = v.x; Ls[r][c4 * 4 + 1] = v.y;
    Ls[r][c4 * 4 + 2] = v.z; Ls[r][c4 * 4 + 3] = v.w;
  }
  __syncthreads();
  const int n = tid >> 2, ch = tid & 3;
  __align__(16) unsigned short tmp[16];
#pragma unroll
  for (int j = 0; j < 16; ++j) tmp[j] = f2bf(Ls[ch * 16 + j][n] * scale);
  unsigned short* dst = Wt + (size_t)(mat * 64 + n) * INS + kt * 64 + ch * 16;
  *reinterpret_cast<int4*>(dst)     = *reinterpret_cast<const int4*>(tmp);
  *reinterpret_cast<int4*>(dst + 8) = *reinterpret_cast<const int4*>(tmp + 8);
  if (kt == 0 && tid < 64) bc[mat * 64 + tid] = bs[tid] * scale;
}

// ---------------- kernel 2: barrier-free QKV GEMM ----------------------------
// wave = 16 rows x 96 channels (N-half). B-frags straight from global (Wt is
// L2/L1-resident, 16-row x 64B perfectly coalesced frag loads). Register-
// rotated prefetch, zero __syncthreads.
__global__ __launch_bounds__(256) void qkv_gemm(
    const float* __restrict__ X, const unsigned short* __restrict__ Wt,
    const float* __restrict__ bc,
    unsigned short* __restrict__ Qg, unsigned short* __restrict__ Kg,
    unsigned short* __restrict__ Vtg) {
  const int tid  = threadIdx.x;
  const int wave = tid >> 6, lane = tid & 63;
  const int quad = lane >> 4, l16 = lane & 15;
  const int rg = wave >> 1;          // row-group (0,1)
  const int ns = wave & 1;           // N-half (0,1)
  const int row = blockIdx.x * 32 + rg * 16 + l16;
  const float* Xr = X + (size_t)row * INS + quad * 8;
  const unsigned short* Wb = Wt + (size_t)ns * 96 * INS;

  f32x4 acc[6];
#pragma unroll
  for (int i = 0; i < 6; ++i) acc[i] = (f32x4){0.f, 0.f, 0.f, 0.f};

  // prefetch chunk 0
  float4 cx0 = *reinterpret_cast<const float4*>(Xr);
  float4 cx1 = *reinterpret_cast<const float4*>(Xr + 4);
  short8 cb[6];
#pragma unroll
  for (int nt = 0; nt < 6; ++nt)
    cb[nt] = *reinterpret_cast<const short8*>(Wb + (size_t)(nt * 16 + l16) * INS + quad * 8);

  for (int kc = 0; kc < 24; ++kc) {
    float4 nx0, nx1; short8 nb[6];
    if (kc + 1 < 24) {
      const int ko = (kc + 1) * 32;
      nx0 = *reinterpret_cast<const float4*>(Xr + ko);
      nx1 = *reinterpret_cast<const float4*>(Xr + ko + 4);
#pragma unroll
      for (int nt = 0; nt < 6; ++nt)
        nb[nt] = *reinterpret_cast<const short8*>(Wb + (size_t)(nt * 16 + l16) * INS + ko + quad * 8);
    }
    short8 a = cvt8(cx0, cx1);
#pragma unroll
    for (int nt = 0; nt < 6; ++nt)
      acc[nt] = __builtin_amdgcn_mfma_f32_16x16x32_bf16(a, cb[nt], acc[nt], 0, 0, 0);
    cx0 = nx0; cx1 = nx1;
#pragma unroll
    for (int nt = 0; nt < 6; ++nt) cb[nt] = nb[nt];
  }

  // epilogue: Q,K row-major bf16; V transposed Vt[batch][d][s]
  const int gm0 = blockIdx.x * 32 + rg * 16 + quad * 4;
#pragma unroll
  for (int nt = 0; nt < 6; ++nt) {
    const int n = ns * 96 + nt * 16 + l16;
    const float bias = bc[n];
    if (n < 128) {
      unsigned short* dstbase = (n < 64) ? Qg : Kg;
      const int nn = n & 63;
#pragma unroll
      for (int r = 0; r < 4; ++r)
        dstbase[(size_t)(gm0 + r) * OUTS + nn] = f2bf(acc[nt][r] + bias);
    } else {
      const int d = n - 128;
      const int batch = gm0 >> 11, s0 = gm0 & 2047;
      ushort4 pk;
      pk.x = f2bf(acc[nt][0] + bias);
      pk.y = f2bf(acc[nt][1] + bias);
      pk.z = f2bf(acc[nt][2] + bias);
      pk.w = f2bf(acc[nt][3] + bias);
      *reinterpret_cast<ushort4*>(&Vtg[((size_t)batch * OUTS + d) * SS + s0]) = pk;
    }
  }
}

// ---------------- kernel 3: barrier-free attention, key-split x4 -------------
// wave = 32 q-rows x 512 keys. K/V B-frags straight from global (L2/L1-hit,
// coalesced). Wave-private LDS only for the P C->A transpose. No syncthreads.
#define LDP 40

__global__ __launch_bounds__(256) void attn(
    const unsigned short* __restrict__ Qg, const unsigned short* __restrict__ Kg,
    const unsigned short* __restrict__ Vtg,
    float* __restrict__ OP, float* __restrict__ LS) {
  __shared__ __align__(16) unsigned short Ps[4][2][16 * LDP];
  const int tid  = threadIdx.x;
  const int wave = tid >> 6, lane = tid & 63;
  const int quad = lane >> 4, l16 = lane & 15;
  const int bt  = blockIdx.x >> 6;
  const int rem = blockIdx.x & 63;
  const int qb  = rem >> 2, ksl = rem & 3;
  const int q0 = qb * 128 + wave * 32;
  const unsigned short* Qb = Qg + (size_t)bt * SS * OUTS;
  const unsigned short* Kb = Kg + (size_t)bt * SS * OUTS;
  const unsigned short* Vb = Vtg + (size_t)bt * OUTS * SS;

  short8 aq[2][2];
#pragma unroll
  for (int mh = 0; mh < 2; ++mh)
#pragma unroll
    for (int ks = 0; ks < 2; ++ks)
      aq[mh][ks] = *reinterpret_cast<const short8*>(
          Qb + (size_t)(q0 + mh * 16 + l16) * OUTS + ks * 32 + quad * 8);

  f32x4 oacc[2][4];
#pragma unroll
  for (int mh = 0; mh < 2; ++mh)
#pragma unroll
    for (int nt = 0; nt < 4; ++nt) oacc[mh][nt] = (f32x4){0.f, 0.f, 0.f, 0.f};
  float lsum[2][4] = {{0.f,0.f,0.f,0.f},{0.f,0.f,0.f,0.f}};

  const int jbeg = ksl * 512;
  for (int j0 = jbeg; j0 < jbeg + 512; j0 += 32) {
    short8 bk[2][2], bv[4];
#pragma unroll
    for (int nt2 = 0; nt2 < 2; ++nt2)
#pragma unroll
      for (int ks = 0; ks < 2; ++ks)
        bk[nt2][ks] = *reinterpret_cast<const short8*>(
            Kb + (size_t)(j0 + nt2 * 16 + l16) * OUTS + ks * 32 + quad * 8);
#pragma unroll
    for (int nt = 0; nt < 4; ++nt)
      bv[nt] = *reinterpret_cast<const short8*>(
          Vb + (size_t)(nt * 16 + l16) * SS + j0 + quad * 8);

#pragma unroll
    for (int mh = 0; mh < 2; ++mh) {
      f32x4 sc[2];
      sc[0] = (f32x4){0.f,0.f,0.f,0.f}; sc[1] = (f32x4){0.f,0.f,0.f,0.f};
#pragma unroll
      for (int ks = 0; ks < 2; ++ks)
#pragma unroll
        for (int nt2 = 0; nt2 < 2; ++nt2)
          sc[nt2] = __builtin_amdgcn_mfma_f32_16x16x32_bf16(aq[mh][ks], bk[nt2][ks], sc[nt2], 0, 0, 0);

      unsigned short* Pw = Ps[wave][mh];
#pragma unroll
      for (int nt2 = 0; nt2 < 2; ++nt2)
#pragma unroll
        for (int r = 0; r < 4; ++r) {
          float p = __expf(sc[nt2][r]);
          lsum[mh][r] += p;
          Pw[(quad * 4 + r) * LDP + nt2 * 16 + l16] = f2bf(p);
        }
      short8 ap = *reinterpret_cast<const short8*>(&Pw[l16 * LDP + quad * 8]);
#pragma unroll
      for (int nt = 0; nt < 4; ++nt)
        oacc[mh][nt] = __builtin_amdgcn_mfma_f32_16x16x32_bf16(ap, bv[nt], oacc[mh][nt], 0, 0, 0);
    }
  }

  // reduce lsum across the 16 l16-lanes (row owners share quad)
#pragma unroll
  for (int st = 1; st < 16; st <<= 1)
#pragma unroll
    for (int mh = 0; mh < 2; ++mh)
#pragma unroll
      for (int r = 0; r < 4; ++r) lsum[mh][r] += __shfl_xor(lsum[mh][r], st, 64);

  float* OPb = OP + ((size_t)ksl * BB + bt) * SS * OUTS;
#pragma unroll
  for (int mh = 0; mh < 2; ++mh)
#pragma unroll
    for (int nt = 0; nt < 4; ++nt)
#pragma unroll
      for (int r = 0; r < 4; ++r) {
        int q = q0 + mh * 16 + quad * 4 + r;
        OPb[(size_t)q * OUTS + nt * 16 + l16] = oacc[mh][nt][r];
      }
  if (l16 == 0) {
#pragma unroll
    for (int mh = 0; mh < 2; ++mh)
#pragma unroll
      for (int r = 0; r < 4; ++r)
        LS[(size_t)ksl * BB * SS + bt * SS + q0 + mh * 16 + quad * 4 + r] = lsum[mh][r];
  }
}

// ---------------- kernel 4: combine key-split partials -----------------------
__global__ __launch_bounds__(256) void combine(
    const float* __restrict__ OP, const float* __restrict__ LS,
    float* __restrict__ out) {
  const size_t i4 = (size_t)blockIdx.x * 256 + threadIdx.x;  // float4 index
  const size_t row = (i4 * 4) >> 6;                          // bt*S + q
  float4 o = make_float4(0.f, 0.f, 0.f, 0.f);
  float l = 0.f;
#pragma unroll
  for (int ks = 0; ks < 4; ++ks) {
    float4 t = reinterpret_cast<const float4*>(OP + (size_t)ks * BB * SS * OUTS)[i4];
    o.x += t.x; o.y += t.y; o.z += t.z; o.w += t.w;
    l += LS[(size_t)ks * BB * SS + row];
  }
  const float inv = 1.0f / l;
  reinterpret_cast<float4*>(out)[i4] = make_float4(o.x * inv, o.y * inv, o.z * inv, o.w * inv);
}

extern "C" void kernel_launch(void* const* d_in, const int* in_sizes, int n_in,
                              void* d_out, int out_size, void* d_ws, size_t ws_size,
                              hipStream_t stream) {
  const float* X  = (const float*)d_in[0];
  const float* Wq = (const float*)d_in[1];
  const float* bq = (const float*)d_in[2];
  const float* Wk = (const float*)d_in[3];
  const float* bk = (const float*)d_in[4];
  const float* Wv = (const float*)d_in[5];
  const float* bv = (const float*)d_in[6];
  float* out = (float*)d_out;

  char* ws = (char*)d_ws;
  unsigned short* Qg  = (unsigned short*)(ws);                              // 2 MB
  unsigned short* Kg  = (unsigned short*)(ws + (size_t)2 * 1024 * 1024);    // 2 MB
  unsigned short* Vtg = (unsigned short*)(ws + (size_t)4 * 1024 * 1024);    // 2 MB
  unsigned short* Wt  = (unsigned short*)(ws + (size_t)6 * 1024 * 1024);    // 288 KB
  float*          bc  = (float*)(ws + (size_t)6 * 1024 * 1024 + 294912);    // 768 B
  float*          OP  = (float*)(ws + (size_t)7 * 1024 * 1024);             // 16 MB
  float*          LS  = (float*)(ws + (size_t)23 * 1024 * 1024);            // 256 KB

  cast_weights<<<36, 256, 0, stream>>>(Wq, bq, Wk, bk, Wv, bv, Wt, bc);
  qkv_gemm<<<512, 256, 0, stream>>>(X, Wt, bc, Qg, Kg, Vtg);
  attn<<<512, 256, 0, stream>>>(Qg, Kg, Vtg, OP, LS);
  combine<<<1024, 256, 0, stream>>>(OP, LS, out);
}